// Round 15
// baseline (1518.879 us; speedup 1.0000x reference)
//
#include <hip/hip_runtime.h>
#include <hip/hip_bf16.h>

#define BATCH 128
#define SEQ   80
#define EMB   100
#define UNITS 2048

typedef __attribute__((ext_vector_type(8))) short bf16x8;
typedef __attribute__((ext_vector_type(4))) float f32x4;

static __device__ __forceinline__ short f2bf(float f) {
  __hip_bfloat16 h = __float2bfloat16(f);
  return *reinterpret_cast<short*>(&h);
}
static __device__ __forceinline__ float bf2f(short s) {
  __hip_bfloat16 h = *reinterpret_cast<__hip_bfloat16*>(&s);
  return __bfloat162float(h);
}

// Packed fragment layouts (nch = K/32):
//  A-pack (h, E): elem(row m, k) at [r=m>>4][kk=k>>5][lane=(m&15)|(((k>>3)&3)<<4)][j=k&7]
//  B-pack (W):    elem(k, col n) at [c=n>>4][kk=k>>5][lane=(n&15)|(((k>>3)&3)<<4)][j=k&7]
// Units of 1 KB (64 lanes x 16 B); staging is a linear 16B/lane copy.
// E and W0 zero-padded to K=256 (8 kk) so layer 0 runs the same uniform
// BK=256 step structure (9 steps) as layers 1-3 (16 steps).

__global__ __launch_bounds__(256) void pack_b_kernel(
    const float* __restrict__ src, int Ksrc, int N, int nch, int totalUnits,
    short* __restrict__ dst) {
  int lane = threadIdx.x & 63;
  int u = blockIdx.x * 4 + (threadIdx.x >> 6);
  if (u >= totalUnits) return;
  int c  = u / nch;
  int kk = u - c * nch;
  int n  = c * 16 + (lane & 15);
  int k0 = kk * 32 + ((lane >> 4) << 3);
  bf16x8 v;
#pragma unroll
  for (int j = 0; j < 8; ++j) {
    int k = k0 + j;
    float f = (k < Ksrc) ? src[k * N + n] : 0.f;
    v[j] = f2bf(f);
  }
  *reinterpret_cast<bf16x8*>(dst + (u * 64 + lane) * 8) = v;
}

// E padded to 8 kk-chunks: Ep2[t][r(8)][kq(8)][lane][8]
__global__ __launch_bounds__(256) void pack_e_kernel(
    const int* __restrict__ tokens, const float* __restrict__ emb,
    short* __restrict__ Ep2) {
  int idx = blockIdx.x * 256 + threadIdx.x;   // ((t*8+r)*8+kq)*64+lane
  if (idx >= SEQ * 8 * 8 * 64) return;
  int lane = idx & 63;
  int kq = (idx >> 6) & 7;
  int r  = (idx >> 9) & 7;
  int t  = idx >> 12;
  int b  = r * 16 + (lane & 15);
  int k0 = kq * 32 + ((lane >> 4) << 3);
  int tok = tokens[b * SEQ + t];
  bf16x8 v;
#pragma unroll
  for (int j = 0; j < 8; ++j) {
    int k = k0 + j;
    v[j] = (k < EMB) ? f2bf(emb[tok * EMB + k]) : (short)0;
  }
  *reinterpret_cast<bf16x8*>(Ep2 + (size_t)idx * 8) = v;
}

// ---------------------------------------------------------------------------
// Diagonal stage, 2-blocks-per-CU occupancy structure.
// Grid 512 = 4 l x 32 cb x 4 row-strips (rs); block 512 thr = 8 waves
// (wc2 x wk4); tile = 32 rows x 64 cols; BK=256.
//  - A panels: LDS ring-4 x 16 KB (64 KB total -> 2 blocks/CU), staged via
//    global_load_lds (2 x 16B per thread per step).
//  - B: registers, asm dwordx4 (4/wave/step), depth-1 double-buffered.
//  - ONE s_barrier per step; exact vmcnt ledger (per thread):
//    prologue [A0:2,B0:4,A1:2]=8; STEP(g) issues B(g+1):4,A(g+2):2 -> 14,
//    leave newest 8 (completes A(g),B(g)); tails 6, 0.
//  - K-split-4 (wk) partials reduced into wk=0 via LDS in FIXED order.
// Stalls of the two co-resident blocks decorrelate -> latency hiding.
// ---------------------------------------------------------------------------
#define MFMA(a, b, c) __builtin_amdgcn_mfma_f32_16x16x32_bf16((a), (b), (c), 0, 0, 0)

static __device__ __forceinline__ void gload16(const void* g, void* l) {
  __builtin_amdgcn_global_load_lds(
      (const __attribute__((address_space(1))) void*)g,
      (__attribute__((address_space(3))) void*)l, 16, 0, 0);
}

struct BF { bf16x8 v[2][2]; };   // [y][kqi]

#define WAITV(N) asm volatile("s_waitcnt vmcnt(" #N ")" ::: "memory")

__global__ __launch_bounds__(512) void diag_kernel(
    const short* __restrict__ Ep2,
    const short* __restrict__ W0p, const short* __restrict__ U0p,
    const short* __restrict__ Wsp, const short* __restrict__ Usp,
    const float* __restrict__ b0, const float* __restrict__ b1,
    short* __restrict__ hbase, int s) {
  __shared__ char lds[65536];   // ring-4 x 16 KB; reused for wk reduction

  const int tid  = threadIdx.x;
  const int lane = tid & 63;
  const int w    = tid >> 6;
  const int wc = w & 1, wk = w >> 1;   // wk = 0..3 (kq-pair slice)

  // XCD-affine mapping: xcd = bid & 7 owns 4 consecutive cb's x all (rs,l)
  int bid = blockIdx.x;
  int xcd = bid & 7, idx = bid >> 3;      // idx 0..63
  int cb   = xcd * 4 + (idx & 3);         // 0..31
  int rem2 = idx >> 2;                    // 0..15
  int rs   = rem2 & 3;                    // row strip (32 rows)
  int l    = rem2 >> 2;
  int t    = s - l;
  if (t < 0 || t >= SEQ) return;

  const size_t hsz = (size_t)8 * 64 * 64 * 8;
  const int pw = s & 1, pr = pw ^ 1;
  auto hb = [&](int ll, int p) { return hbase + (size_t)(ll * 2 + p) * hsz; };

  // ---- segment config ----
  const char *Aseg0, *Aseg1, *Bseg0, *Bseg1;
  size_t aRow0;          // r-tile byte stride of seg0 A
  int nchB0;             // c-tile chunk count of seg0 B
  int steps0, total;
  if (l == 0) {
    Aseg0 = (const char*)(Ep2 + (size_t)t * 32768); aRow0 = 8192;
    Bseg0 = (const char*)W0p; nchB0 = 8;
    Aseg1 = (const char*)hb(0, pr);
    Bseg1 = (const char*)U0p;
    steps0 = 1; total = 9;
  } else {
    Aseg0 = (const char*)hb(l - 1, pr); aRow0 = 65536;
    Bseg0 = (const char*)Wsp; nchB0 = 64;
    Aseg1 = (const char*)hb(l, pr);
    Bseg1 = (const char*)Usp;
    steps0 = 8; total = 16;
  }
  const int rt0 = rs * 2;                 // first r-tile of this strip
  const size_t lb16 = (size_t)lane * 16;

  // ---- A staging: thread stages units (x=0, kq=uA) and (x=1, kq=uA) ----
  const int uA = tid >> 6;                // 0..7 = kq within step
  const char* a0T = Aseg0 + (size_t)rt0 * aRow0 + (size_t)uA * 1024 + lb16;
  const char* a1T = Aseg1 + (size_t)rt0 * 65536 + (size_t)uA * 1024 + lb16;
  char* dT = &lds[0] + (size_t)uA * 1024 + lb16;

  auto issueA = [&](int g) {
    char* dst = dT + (size_t)(g & 3) * 16384;
    const char* src; size_t xstr;
    if (g < steps0) { src = a0T + (size_t)g * 8192; xstr = aRow0; }
    else            { src = a1T + (size_t)(g - steps0) * 8192; xstr = 65536; }
    gload16(src, dst);                  // x = 0
    gload16(src + xstr, dst + 8192);    // x = 1
  };

  // ---- B: wave's 2 cols (cb*4 + wc*2 + y), kq = 2wk + kqi ----
  const char* bS0[2], *bS1[2];
  bS0[0] = Bseg0 + ((size_t)(cb * 4 + wc * 2 + 0) * nchB0 + wk * 2) * 1024 + lb16;
  bS0[1] = Bseg0 + ((size_t)(cb * 4 + wc * 2 + 1) * nchB0 + wk * 2) * 1024 + lb16;
  bS1[0] = Bseg1 + ((size_t)(cb * 4 + wc * 2 + 0) * 64 + wk * 2) * 1024 + lb16;
  bS1[1] = Bseg1 + ((size_t)(cb * 4 + wc * 2 + 1) * 64 + wk * 2) * 1024 + lb16;

#define LOADB(BN, GS)                                                         \
  do {                                                                        \
    const int gs_ = (GS);                                                     \
    const char *p0_, *p1_;                                                    \
    if (gs_ < steps0) {                                                       \
      size_t o_ = (size_t)gs_ * 8192;                                         \
      p0_ = bS0[0] + o_; p1_ = bS0[1] + o_;                                   \
    } else {                                                                  \
      size_t o_ = (size_t)(gs_ - steps0) * 8192;                              \
      p0_ = bS1[0] + o_; p1_ = bS1[1] + o_;                                   \
    }                                                                         \
    asm volatile("global_load_dwordx4 %0, %1, off" : "=v"(BN.v[0][0]) : "v"(p0_));        \
    asm volatile("global_load_dwordx4 %0, %1, off" : "=v"(BN.v[0][1]) : "v"(p0_ + 1024)); \
    asm volatile("global_load_dwordx4 %0, %1, off" : "=v"(BN.v[1][0]) : "v"(p1_));        \
    asm volatile("global_load_dwordx4 %0, %1, off" : "=v"(BN.v[1][1]) : "v"(p1_ + 1024)); \
  } while (0)

  f32x4 acc[2][2];
#pragma unroll
  for (int x = 0; x < 2; ++x)
#pragma unroll
    for (int y = 0; y < 2; ++y) acc[x][y] = (f32x4){0.f, 0.f, 0.f, 0.f};

  auto computeStep = [&](int g, const BF& Bf) {
    const char* base = &lds[0] + (size_t)(g & 3) * 16384;
#pragma unroll
    for (int x = 0; x < 2; ++x) {
      bf16x8 av0 = *(const bf16x8*)(base + (((x * 8 + wk * 2 + 0) << 10) + lb16));
      bf16x8 av1 = *(const bf16x8*)(base + (((x * 8 + wk * 2 + 1) << 10) + lb16));
#pragma unroll
      for (int y = 0; y < 2; ++y) {
        acc[x][y] = MFMA(av0, Bf.v[y][0], acc[x][y]);
        acc[x][y] = MFMA(av1, Bf.v[y][1], acc[x][y]);
      }
    }
  };

  // ledger (per thread): entering STEP(g): [A(g):2,B(g):4,A(g+1):2] = 8.
  // Issue B(g+1):4, A(g+2):2 -> 14; leave newest 8 -> A(g),B(g) complete.
  // g=total-2: issue B only -> 12; leave 6. g=total-1: leave 0.
#define STEP(G, BCUR, BNXT)                                          \
  do {                                                               \
    const int g_ = (G);                                              \
    if (g_ + 1 < total) LOADB(BNXT, g_ + 1);                         \
    if (g_ + 2 < total) issueA(g_ + 2);                              \
    if (g_ + 2 < total) { WAITV(8); }                                \
    else if (g_ + 1 < total) { WAITV(6); }                           \
    else { WAITV(0); }                                               \
    __builtin_amdgcn_s_barrier();                                    \
    __builtin_amdgcn_sched_barrier(0);                               \
    computeStep(g_, BCUR);                                           \
    __builtin_amdgcn_sched_barrier(0);                               \
  } while (0)

  BF Bq0, Bq1;
  issueA(0); LOADB(Bq0, 0); issueA(1);

  for (int g = 0; g < total; g += 2) {
    STEP(g, Bq0, Bq1);
    if (g + 1 < total) STEP(g + 1, Bq1, Bq0);
  }
#undef STEP
#undef LOADB

  // ---- K-split-4 reduction: wk=1..3 -> LDS (24 KB) -> wk=0, fixed order ----
  __syncthreads();
  if (wk != 0) {
    char* d = &lds[0] + ((size_t)((wk - 1) * 2 + wc) << 12);
#pragma unroll
    for (int x = 0; x < 2; ++x)
#pragma unroll
      for (int y = 0; y < 2; ++y)
        *(f32x4*)(d + (((x * 2 + y) << 10) + lb16)) = acc[x][y];
  }
  __syncthreads();
  if (wk != 0) return;
#pragma unroll
  for (int p = 0; p < 3; ++p) {
    const char* sp = &lds[0] + ((size_t)(p * 2 + wc) << 12);
#pragma unroll
    for (int x = 0; x < 2; ++x)
#pragma unroll
      for (int y = 0; y < 2; ++y)
        acc[x][y] += *(const f32x4*)(sp + (((x * 2 + y) << 10) + lb16));
  }

  // Epilogue: bias + tanh, store into A-pack layout of h_l (parity pw).
  // C/D layout: col = lane&15, row = (lane>>4)*4 + i.
  const float* bias = (l == 0) ? b0 : b1;
  short* H = hb(l, pw);
  const int lo = lane & 15, hi = lane >> 4;
  const int nb = cb * 64 + wc * 32;
  const float bv0 = bias[nb + lo];
  const float bv1 = bias[nb + 16 + lo];
#pragma unroll
  for (int x = 0; x < 2; ++x)
#pragma unroll
    for (int y = 0; y < 2; ++y) {
      float bbv = y ? bv1 : bv0;
#pragma unroll
      for (int i = 0; i < 4; ++i) {
        int m = rs * 32 + x * 16 + hi * 4 + i;
        int n = nb + y * 16 + lo;
        float z = acc[x][y][i] + bbv;
        float e = __expf(2.f * z);
        float th = 1.f - 2.f / (e + 1.f);
        int rr = m >> 4, kk = n >> 5;
        int lp = (m & 15) | (((n >> 3) & 3) << 4);
        H[(((size_t)rr * 64 + kk) * 64 + lp) * 8 + (n & 7)] = f2bf(th);
      }
    }
}

// ---------------------------------------------------------------------------
// Output head: out[b] = sigmoid(h3[b] . Wo + bo); h3 in A-pack layout.
// ---------------------------------------------------------------------------
__global__ __launch_bounds__(256) void head_kernel(
    const short* __restrict__ h3, const float* __restrict__ Wo,
    const float* __restrict__ bo, float* __restrict__ out) {
  __shared__ float sred[4];
  int b = blockIdx.x, tid = threadIdx.x;
  int kk = tid >> 2, hi = tid & 3;
  const bf16x8 v = *reinterpret_cast<const bf16x8*>(
      h3 + (((size_t)(b >> 4) * 64 + kk) * 64 + ((b & 15) | (hi << 4))) * 8);
  int k0 = kk * 32 + hi * 8;
  float acc = 0.f;
#pragma unroll
  for (int j = 0; j < 8; ++j) acc += bf2f(v[j]) * Wo[k0 + j];
  for (int off = 32; off > 0; off >>= 1) acc += __shfl_down(acc, off);
  if ((tid & 63) == 0) sred[tid >> 6] = acc;
  __syncthreads();
  if (tid == 0) {
    float z = sred[0] + sred[1] + sred[2] + sred[3] + bo[0];
    out[b] = 1.f / (1.f + expf(-z));
  }
}

extern "C" void kernel_launch(void* const* d_in, const int* in_sizes, int n_in,
                              void* d_out, int out_size, void* d_ws, size_t ws_size,
                              hipStream_t stream) {
  const int*   tokens = (const int*)d_in[0];
  const float* emb    = (const float*)d_in[1];
  const float* W0     = (const float*)d_in[2];
  const float* U0     = (const float*)d_in[3];
  const float* b0     = (const float*)d_in[4];
  const float* W1     = (const float*)d_in[5];
  const float* U1     = (const float*)d_in[6];
  const float* b1     = (const float*)d_in[7];
  const float* Wo     = (const float*)d_in[8];
  const float* bo     = (const float*)d_in[9];
  float* out = (float*)d_out;
  short* ws  = (short*)d_ws;

  const size_t W0P_SZ = (size_t)128 * 8 * 512;     // 524288  (padded to 8 kk)
  const size_t UP_SZ  = (size_t)128 * 64 * 512;    // 4194304
  const size_t EP_SZ  = (size_t)SEQ * 32768;       // 2621440 (padded to 8 kk)
  const size_t H_SZ   = (size_t)8 * 64 * 64 * 8;   // 262144 per buffer

  short* W0p = ws;
  short* U0p = W0p + W0P_SZ;
  short* W1p = U0p + UP_SZ;
  short* U1p = W1p + UP_SZ;
  short* Ep2 = U1p + UP_SZ;
  short* hbase = Ep2 + EP_SZ;

  {
    int unitsW0 = (UNITS / 16) * 8;             // 1024 (8 kk, zero-padded)
    pack_b_kernel<<<(unitsW0 + 3) / 4, 256, 0, stream>>>(W0, EMB, UNITS, 8, unitsW0, W0p);
    int unitsU = (UNITS / 16) * (UNITS / 32);   // 8192
    pack_b_kernel<<<(unitsU + 3) / 4, 256, 0, stream>>>(U0, UNITS, UNITS, UNITS / 32, unitsU, U0p);
    pack_b_kernel<<<(unitsU + 3) / 4, 256, 0, stream>>>(W1, UNITS, UNITS, UNITS / 32, unitsU, W1p);
    pack_b_kernel<<<(unitsU + 3) / 4, 256, 0, stream>>>(U1, UNITS, UNITS, UNITS / 32, unitsU, U1p);
    int ne = SEQ * 8 * 8 * 64;
    pack_e_kernel<<<(ne + 255) / 256, 256, 0, stream>>>(tokens, emb, Ep2);
  }

  // zero all 8 h double-buffers (provides h_l[-1] = 0)
  hipMemsetAsync(hbase, 0, 8u * H_SZ * 2u, stream);

  // ---- 83 diagonals: s = t + l ----
  for (int s = 0; s <= SEQ - 1 + 3; ++s) {
    diag_kernel<<<512, 512, 0, stream>>>(Ep2, W0p, U0p, W1p, U1p, b0, b1, hbase, s);
  }

  // final head: h3[SEQ-1] written at diagonal 82 (parity 0)
  head_kernel<<<BATCH, 256, 0, stream>>>(hbase + 6 * H_SZ, Wo, bo, out);
}

// Round 16
// 1374.845 us; speedup vs baseline: 1.1048x; 1.1048x over previous
//
#include <hip/hip_runtime.h>
#include <hip/hip_bf16.h>

#define BATCH 128
#define SEQ   80
#define EMB   100
#define UNITS 2048

typedef __attribute__((ext_vector_type(8))) short bf16x8;
typedef __attribute__((ext_vector_type(4))) float f32x4;

static __device__ __forceinline__ short f2bf(float f) {
  __hip_bfloat16 h = __float2bfloat16(f);
  return *reinterpret_cast<short*>(&h);
}
static __device__ __forceinline__ float bf2f(short s) {
  __hip_bfloat16 h = *reinterpret_cast<__hip_bfloat16*>(&s);
  return __bfloat162float(h);
}

// Packed fragment layouts (nch = K/32):
//  A-pack (h, E): elem(row m, k) at [r=m>>4][kk=k>>5][lane=(m&15)|(((k>>3)&3)<<4)][j=k&7]
//  B-pack (W):    elem(k, col n) at [c=n>>4][kk=k>>5][lane=(n&15)|(((k>>3)&3)<<4)][j=k&7]
// Units of 1 KB (64 lanes x 16 B); staging is a linear 16B/lane copy.
// E and W0 zero-padded to K=256 (8 kk) so layer 0 runs the same uniform
// BK=256 step structure (9 steps) as layers 1-3 (16 steps).

__global__ __launch_bounds__(256) void pack_b_kernel(
    const float* __restrict__ src, int Ksrc, int N, int nch, int totalUnits,
    short* __restrict__ dst) {
  int lane = threadIdx.x & 63;
  int u = blockIdx.x * 4 + (threadIdx.x >> 6);
  if (u >= totalUnits) return;
  int c  = u / nch;
  int kk = u - c * nch;
  int n  = c * 16 + (lane & 15);
  int k0 = kk * 32 + ((lane >> 4) << 3);
  bf16x8 v;
#pragma unroll
  for (int j = 0; j < 8; ++j) {
    int k = k0 + j;
    float f = (k < Ksrc) ? src[k * N + n] : 0.f;
    v[j] = f2bf(f);
  }
  *reinterpret_cast<bf16x8*>(dst + (u * 64 + lane) * 8) = v;
}

// E padded to 8 kk-chunks: Ep2[t][r(8)][kq(8)][lane][8]
__global__ __launch_bounds__(256) void pack_e_kernel(
    const int* __restrict__ tokens, const float* __restrict__ emb,
    short* __restrict__ Ep2) {
  int idx = blockIdx.x * 256 + threadIdx.x;   // ((t*8+r)*8+kq)*64+lane
  if (idx >= SEQ * 8 * 8 * 64) return;
  int lane = idx & 63;
  int kq = (idx >> 6) & 7;
  int r  = (idx >> 9) & 7;
  int t  = idx >> 12;
  int b  = r * 16 + (lane & 15);
  int k0 = kq * 32 + ((lane >> 4) << 3);
  int tok = tokens[b * SEQ + t];
  bf16x8 v;
#pragma unroll
  for (int j = 0; j < 8; ++j) {
    int k = k0 + j;
    v[j] = (k < EMB) ? f2bf(emb[tok * EMB + k]) : (short)0;
  }
  *reinterpret_cast<bf16x8*>(Ep2 + (size_t)idx * 8) = v;
}

// ---------------------------------------------------------------------------
// Diagonal stage. 1024 threads = 16 waves = wc2 x wk8 (NO wr axis -> every
// L2 byte is loaded exactly once). Block = 64x64 output tile, BK=256.
// Wave (wc,wk): per step 4 ds_read_b128 (r-tiles 0..3 at kq=wk) + 2 B-loads
// (cols wc*2+{0,1} at kq=wk) + 8 MFMA. Issued L2/step = A 32 KB + B 32 KB
// (both unique) at 4 waves/SIMD TLP.
//  - A panels: LDS ring-4 x 32 KB (128 KB), global_load_lds (2/thread/step).
//  - B: registers, asm dwordx4 (2/thread/step), depth-1 double-buffered.
//  - ONE s_barrier per step; exact vmcnt ledger (per thread):
//    entering STEP(g): [A(g):2,B(g):2,A(g+1):2]=6; issue B(g+1):2,A(g+2):2
//    -> 10; leave newest 6. Tails: 4, then 0.
//  - wk=1..7 partials reduced into wk=0 via LDS (112 KB) in FIXED order.
// ---------------------------------------------------------------------------
#define MFMA(a, b, c) __builtin_amdgcn_mfma_f32_16x16x32_bf16((a), (b), (c), 0, 0, 0)

static __device__ __forceinline__ void gload16(const void* g, void* l) {
  __builtin_amdgcn_global_load_lds(
      (const __attribute__((address_space(1))) void*)g,
      (__attribute__((address_space(3))) void*)l, 16, 0, 0);
}

struct BF { bf16x8 v[2]; };   // [y]

#define WAITV(N) asm volatile("s_waitcnt vmcnt(" #N ")" ::: "memory")

__global__ __launch_bounds__(1024) void diag_kernel(
    const short* __restrict__ Ep2,
    const short* __restrict__ W0p, const short* __restrict__ U0p,
    const short* __restrict__ Wsp, const short* __restrict__ Usp,
    const float* __restrict__ b0, const float* __restrict__ b1,
    short* __restrict__ hbase, int s) {
  __shared__ char lds[131072];   // ring-4 x 32 KB; reused for wk reduction

  const int tid  = threadIdx.x;
  const int lane = tid & 63;
  const int w    = tid >> 6;
  const int wc = w & 1, wk = w >> 1;   // wk = 0..7 (kq slice)

  // XCD-affine mapping: xcd = bid & 7 owns 4 consecutive cb's x all rb's
  int bid = blockIdx.x;
  int xcd = bid & 7, idx = bid >> 3;
  int cb  = xcd * 4 + (idx & 3);   // 0..31
  int rb  = idx >> 2;              // 0..7
  int l   = rb >> 1;
  int t   = s - l;
  if (t < 0 || t >= SEQ) return;

  const size_t hsz = (size_t)8 * 64 * 64 * 8;
  const int pw = s & 1, pr = pw ^ 1;
  auto hb = [&](int ll, int p) { return hbase + (size_t)(ll * 2 + p) * hsz; };

  // ---- segment config (seg0 then seg1, uniform BK=256 steps) ----
  const char *Aseg0, *Aseg1, *Bseg0, *Bseg1;
  size_t aRow0;          // r-tile byte stride of seg0 A
  int nchB0;             // per-c-tile chunk count of seg0 B
  int steps0, total;
  if (l == 0) {
    Aseg0 = (const char*)(Ep2 + (size_t)t * 32768); aRow0 = 8192;
    Bseg0 = (const char*)W0p; nchB0 = 8;
    Aseg1 = (const char*)hb(0, pr);
    Bseg1 = (const char*)U0p;
    steps0 = 1; total = 9;
  } else {
    Aseg0 = (const char*)hb(l - 1, pr); aRow0 = 65536;
    Bseg0 = (const char*)Wsp; nchB0 = 64;
    Aseg1 = (const char*)hb(l, pr);
    Bseg1 = (const char*)Usp;
    steps0 = 8; total = 16;
  }
  const int rloc0 = (rb & 1) * 4;    // layer-local r-tile base
  const size_t lb16 = (size_t)lane * 16;

  // ---- A staging: wave w stages units u = 2w, 2w+1 (rt = w>>2, kq pair) ----
  const int rtA = w >> 2;            // 0..3
  const int kqA = (w & 3) * 2;       // 0,2,4,6
  const char* a0T = Aseg0 + (size_t)(rloc0 + rtA) * aRow0 + (size_t)kqA * 1024 + lb16;
  const char* a1T = Aseg1 + (size_t)(rloc0 + rtA) * 65536 + (size_t)kqA * 1024 + lb16;
  char* dT = &lds[0] + ((size_t)(rtA * 8 + kqA) << 10) + lb16;

  auto issueA = [&](int g) {
    char* dst = dT + (size_t)(g & 3) * 32768;
    const char* src = (g < steps0) ? a0T + (size_t)g * 8192
                                   : a1T + (size_t)(g - steps0) * 8192;
    gload16(src, dst);
    gload16(src + 1024, dst + 1024);
  };

  // ---- B: wave's 2 cols (cb*4 + wc*2 + {0,1}), kq = wk ----
  const char* bS0[2], *bS1[2];
  bS0[0] = Bseg0 + ((size_t)(cb * 4 + wc * 2 + 0) * nchB0 + wk) * 1024 + lb16;
  bS0[1] = Bseg0 + ((size_t)(cb * 4 + wc * 2 + 1) * nchB0 + wk) * 1024 + lb16;
  bS1[0] = Bseg1 + ((size_t)(cb * 4 + wc * 2 + 0) * 64 + wk) * 1024 + lb16;
  bS1[1] = Bseg1 + ((size_t)(cb * 4 + wc * 2 + 1) * 64 + wk) * 1024 + lb16;

#define LOADB(BN, GS)                                                         \
  do {                                                                        \
    const int gs_ = (GS);                                                     \
    const char *p0_, *p1_;                                                    \
    if (gs_ < steps0) {                                                       \
      size_t o_ = (size_t)gs_ * 8192;                                         \
      p0_ = bS0[0] + o_; p1_ = bS0[1] + o_;                                   \
    } else {                                                                  \
      size_t o_ = (size_t)(gs_ - steps0) * 8192;                              \
      p0_ = bS1[0] + o_; p1_ = bS1[1] + o_;                                   \
    }                                                                         \
    asm volatile("global_load_dwordx4 %0, %1, off" : "=v"(BN.v[0]) : "v"(p0_)); \
    asm volatile("global_load_dwordx4 %0, %1, off" : "=v"(BN.v[1]) : "v"(p1_)); \
  } while (0)

  f32x4 acc[4][2];
#pragma unroll
  for (int x = 0; x < 4; ++x)
#pragma unroll
    for (int y = 0; y < 2; ++y) acc[x][y] = (f32x4){0.f, 0.f, 0.f, 0.f};

  auto computeStep = [&](int g, const BF& Bf) {
    const char* base = &lds[0] + (size_t)(g & 3) * 32768;
#pragma unroll
    for (int x = 0; x < 4; ++x) {
      bf16x8 av = *(const bf16x8*)(base + (((x * 8 + wk) << 10) + lb16));
      acc[x][0] = MFMA(av, Bf.v[0], acc[x][0]);
      acc[x][1] = MFMA(av, Bf.v[1], acc[x][1]);
    }
  };

  // ledger (per thread): entering STEP(g): [A(g):2,B(g):2,A(g+1):2] = 6.
  // Issue B(g+1):2, A(g+2):2 -> 10; leave newest 6 -> A(g),B(g) complete.
  // g=total-2: issue B only -> 8; leave 4. g=total-1: leave 0.
#define STEP(G, BCUR, BNXT)                                          \
  do {                                                               \
    const int g_ = (G);                                              \
    if (g_ + 1 < total) LOADB(BNXT, g_ + 1);                         \
    if (g_ + 2 < total) issueA(g_ + 2);                              \
    if (g_ + 2 < total) { WAITV(6); }                                \
    else if (g_ + 1 < total) { WAITV(4); }                           \
    else { WAITV(0); }                                               \
    __builtin_amdgcn_s_barrier();                                    \
    __builtin_amdgcn_sched_barrier(0);                               \
    computeStep(g_, BCUR);                                           \
    __builtin_amdgcn_sched_barrier(0);                               \
  } while (0)

  BF Bq0, Bq1;
  issueA(0); LOADB(Bq0, 0); issueA(1);

  for (int g = 0; g < total; g += 2) {
    STEP(g, Bq0, Bq1);
    if (g + 1 < total) STEP(g + 1, Bq1, Bq0);
  }
#undef STEP
#undef LOADB

  // ---- K-split-8 reduction: wk=1..7 -> LDS (112 KB) -> wk=0, fixed order ----
  __syncthreads();
  if (wk != 0) {
    char* d = &lds[0] + ((size_t)((wk - 1) * 2 + wc) << 13);
#pragma unroll
    for (int x = 0; x < 4; ++x)
#pragma unroll
      for (int y = 0; y < 2; ++y)
        *(f32x4*)(d + (((x * 2 + y) << 10) + lb16)) = acc[x][y];
  }
  __syncthreads();
  if (wk != 0) return;
#pragma unroll
  for (int p = 0; p < 7; ++p) {
    const char* sp = &lds[0] + ((size_t)(p * 2 + wc) << 13);
#pragma unroll
    for (int x = 0; x < 4; ++x)
#pragma unroll
      for (int y = 0; y < 2; ++y)
        acc[x][y] += *(const f32x4*)(sp + (((x * 2 + y) << 10) + lb16));
  }

  // Epilogue: bias + tanh, store into A-pack layout of h_l (parity pw).
  // C/D layout: col = lane&15, row = (lane>>4)*4 + i.
  const float* bias = (l == 0) ? b0 : b1;
  short* H = hb(l, pw);
  const int lo = lane & 15, hi = lane >> 4;
  const int mb = (rb & 1) * 64;
  const int nb = cb * 64 + wc * 32;
  const float bv0 = bias[nb + lo];
  const float bv1 = bias[nb + 16 + lo];
#pragma unroll
  for (int x = 0; x < 4; ++x)
#pragma unroll
    for (int y = 0; y < 2; ++y) {
      float bbv = y ? bv1 : bv0;
#pragma unroll
      for (int i = 0; i < 4; ++i) {
        int m = mb + x * 16 + hi * 4 + i;
        int n = nb + y * 16 + lo;
        float z = acc[x][y][i] + bbv;
        float e = __expf(2.f * z);
        float th = 1.f - 2.f / (e + 1.f);
        int rr = m >> 4, kk = n >> 5;
        int lp = (m & 15) | (((n >> 3) & 3) << 4);
        H[(((size_t)rr * 64 + kk) * 64 + lp) * 8 + (n & 7)] = f2bf(th);
      }
    }
}

// ---------------------------------------------------------------------------
// Output head: out[b] = sigmoid(h3[b] . Wo + bo); h3 in A-pack layout.
// ---------------------------------------------------------------------------
__global__ __launch_bounds__(256) void head_kernel(
    const short* __restrict__ h3, const float* __restrict__ Wo,
    const float* __restrict__ bo, float* __restrict__ out) {
  __shared__ float sred[4];
  int b = blockIdx.x, tid = threadIdx.x;
  int kk = tid >> 2, hi = tid & 3;
  const bf16x8 v = *reinterpret_cast<const bf16x8*>(
      h3 + (((size_t)(b >> 4) * 64 + kk) * 64 + ((b & 15) | (hi << 4))) * 8);
  int k0 = kk * 32 + hi * 8;
  float acc = 0.f;
#pragma unroll
  for (int j = 0; j < 8; ++j) acc += bf2f(v[j]) * Wo[k0 + j];
  for (int off = 32; off > 0; off >>= 1) acc += __shfl_down(acc, off);
  if ((tid & 63) == 0) sred[tid >> 6] = acc;
  __syncthreads();
  if (tid == 0) {
    float z = sred[0] + sred[1] + sred[2] + sred[3] + bo[0];
    out[b] = 1.f / (1.f + expf(-z));
  }
}

extern "C" void kernel_launch(void* const* d_in, const int* in_sizes, int n_in,
                              void* d_out, int out_size, void* d_ws, size_t ws_size,
                              hipStream_t stream) {
  const int*   tokens = (const int*)d_in[0];
  const float* emb    = (const float*)d_in[1];
  const float* W0     = (const float*)d_in[2];
  const float* U0     = (const float*)d_in[3];
  const float* b0     = (const float*)d_in[4];
  const float* W1     = (const float*)d_in[5];
  const float* U1     = (const float*)d_in[6];
  const float* b1     = (const float*)d_in[7];
  const float* Wo     = (const float*)d_in[8];
  const float* bo     = (const float*)d_in[9];
  float* out = (float*)d_out;
  short* ws  = (short*)d_ws;

  const size_t W0P_SZ = (size_t)128 * 8 * 512;     // 524288  (padded to 8 kk)
  const size_t UP_SZ  = (size_t)128 * 64 * 512;    // 4194304
  const size_t EP_SZ  = (size_t)SEQ * 32768;       // 2621440 (padded to 8 kk)
  const size_t H_SZ   = (size_t)8 * 64 * 64 * 8;   // 262144 per buffer

  short* W0p = ws;
  short* U0p = W0p + W0P_SZ;
  short* W1p = U0p + UP_SZ;
  short* U1p = W1p + UP_SZ;
  short* Ep2 = U1p + UP_SZ;
  short* hbase = Ep2 + EP_SZ;

  {
    int unitsW0 = (UNITS / 16) * 8;             // 1024 (8 kk, zero-padded)
    pack_b_kernel<<<(unitsW0 + 3) / 4, 256, 0, stream>>>(W0, EMB, UNITS, 8, unitsW0, W0p);
    int unitsU = (UNITS / 16) * (UNITS / 32);   // 8192
    pack_b_kernel<<<(unitsU + 3) / 4, 256, 0, stream>>>(U0, UNITS, UNITS, UNITS / 32, unitsU, U0p);
    pack_b_kernel<<<(unitsU + 3) / 4, 256, 0, stream>>>(W1, UNITS, UNITS, UNITS / 32, unitsU, W1p);
    pack_b_kernel<<<(unitsU + 3) / 4, 256, 0, stream>>>(U1, UNITS, UNITS, UNITS / 32, unitsU, U1p);
    int ne = SEQ * 8 * 8 * 64;
    pack_e_kernel<<<(ne + 255) / 256, 256, 0, stream>>>(tokens, emb, Ep2);
  }

  // zero all 8 h double-buffers (provides h_l[-1] = 0)
  hipMemsetAsync(hbase, 0, 8u * H_SZ * 2u, stream);

  // ---- 83 diagonals: s = t + l ----
  for (int s = 0; s <= SEQ - 1 + 3; ++s) {
    diag_kernel<<<256, 1024, 0, stream>>>(Ep2, W0p, U0p, W1p, U1p, b0, b1, hbase, s);
  }

  // final head: h3[SEQ-1] written at diagonal 82 (parity 0)
  head_kernel<<<BATCH, 256, 0, stream>>>(hbase + 6 * H_SZ, Wo, bo, out);
}

// Round 17
// 1186.485 us; speedup vs baseline: 1.2802x; 1.1588x over previous
//
#include <hip/hip_runtime.h>
#include <hip/hip_bf16.h>

#define BATCH 128
#define SEQ   80
#define EMB   100
#define UNITS 2048

typedef __attribute__((ext_vector_type(8))) short bf16x8;
typedef __attribute__((ext_vector_type(4))) float f32x4;

static __device__ __forceinline__ short f2bf(float f) {
  __hip_bfloat16 h = __float2bfloat16(f);
  return *reinterpret_cast<short*>(&h);
}
static __device__ __forceinline__ float bf2f(short s) {
  __hip_bfloat16 h = *reinterpret_cast<__hip_bfloat16*>(&s);
  return __bfloat162float(h);
}

// Packed fragment layouts (nch = K/32):
//  A-pack (h, E): elem(row m, k) at [r=m>>4][kk=k>>5][lane=(m&15)|(((k>>3)&3)<<4)][j=k&7]
//  B-pack (W):    elem(k, col n) at [c=n>>4][kk=k>>5][lane=(n&15)|(((k>>3)&3)<<4)][j=k&7]
// Units of 1 KB (64 lanes x 16 B). E and W0 zero-padded to K=256 (8 kk) so
// layer 0 runs the same uniform BK=256 step structure (9 steps) as l>=1 (16).

__global__ __launch_bounds__(256) void pack_b_kernel(
    const float* __restrict__ src, int Ksrc, int N, int nch, int totalUnits,
    short* __restrict__ dst) {
  int lane = threadIdx.x & 63;
  int u = blockIdx.x * 4 + (threadIdx.x >> 6);
  if (u >= totalUnits) return;
  int c  = u / nch;
  int kk = u - c * nch;
  int n  = c * 16 + (lane & 15);
  int k0 = kk * 32 + ((lane >> 4) << 3);
  bf16x8 v;
#pragma unroll
  for (int j = 0; j < 8; ++j) {
    int k = k0 + j;
    float f = (k < Ksrc) ? src[k * N + n] : 0.f;
    v[j] = f2bf(f);
  }
  *reinterpret_cast<bf16x8*>(dst + (u * 64 + lane) * 8) = v;
}

// E padded to 8 kk-chunks: Ep2[t][r(8)][kq(8)][lane][8]
__global__ __launch_bounds__(256) void pack_e_kernel(
    const int* __restrict__ tokens, const float* __restrict__ emb,
    short* __restrict__ Ep2) {
  int idx = blockIdx.x * 256 + threadIdx.x;   // ((t*8+r)*8+kq)*64+lane
  if (idx >= SEQ * 8 * 8 * 64) return;
  int lane = idx & 63;
  int kq = (idx >> 6) & 7;
  int r  = (idx >> 9) & 7;
  int t  = idx >> 12;
  int b  = r * 16 + (lane & 15);
  int k0 = kq * 32 + ((lane >> 4) << 3);
  int tok = tokens[b * SEQ + t];
  bf16x8 v;
#pragma unroll
  for (int j = 0; j < 8; ++j) {
    int k = k0 + j;
    v[j] = (k < EMB) ? f2bf(emb[tok * EMB + k]) : (short)0;
  }
  *reinterpret_cast<bf16x8*>(Ep2 + (size_t)idx * 8) = v;
}

// ---------------------------------------------------------------------------
// Diagonal stage — BARRIER-FREE all-register K-loop.
// 512 threads = 8 waves; wave w owns kq-slice w of each BK=256 step and
// computes the FULL 64x64 tile for that slice (K-split-8). Per step per wave:
// 8 explicit global_load_dwordx4 (A rt=0..3 + B ct=0..3, all block-unique)
// + 16 MFMA into acc[4][4]. No LDS, no s_barrier, no cross-wave coupling in
// the loop: each wave free-runs on its own in-order vmcnt ledger, depth-2
// prefetch via 3 named register sets (period-3 rotation, static indexing).
//   ledger: prologue L(0):8, L(1):8. STEP(g): issue L(g+2):8 -> 24
//   outstanding; vmcnt(16) completes L(g). Tails: 8, then 0.
// End: one __syncthreads pair; 8 partials -> LDS (8 x 16 KB), fixed-order
// sum (deterministic); each wave epilogues 2 of the 16 (rt,ct) cells.
// ---------------------------------------------------------------------------
#define MFMA(a, b, c) __builtin_amdgcn_mfma_f32_16x16x32_bf16((a), (b), (c), 0, 0, 0)

struct FR { bf16x8 a[4]; bf16x8 b[4]; };

#define WAITV(N) asm volatile("s_waitcnt vmcnt(" #N ")" ::: "memory")

__global__ __launch_bounds__(512) void diag_kernel(
    const short* __restrict__ Ep2,
    const short* __restrict__ W0p, const short* __restrict__ U0p,
    const short* __restrict__ Wsp, const short* __restrict__ Usp,
    const float* __restrict__ b0, const float* __restrict__ b1,
    short* __restrict__ hbase, int s) {
  __shared__ char lds[131072];   // used ONLY for the final reduction

  const int tid  = threadIdx.x;
  const int lane = tid & 63;
  const int w    = tid >> 6;     // wave id == kq slice (0..7)

  // XCD-affine mapping: xcd = bid & 7 owns 4 consecutive cb's x all rb's
  int bid = blockIdx.x;
  int xcd = bid & 7, idx = bid >> 3;
  int cb  = xcd * 4 + (idx & 3);   // 0..31
  int rb  = idx >> 2;              // 0..7
  int l   = rb >> 1;
  int t   = s - l;
  if (t < 0 || t >= SEQ) return;

  const size_t hsz = (size_t)8 * 64 * 64 * 8;
  const int pw = s & 1, pr = pw ^ 1;
  auto hb = [&](int ll, int p) { return hbase + (size_t)(ll * 2 + p) * hsz; };

  // ---- segment config (seg0 then seg1, uniform BK=256 steps) ----
  const char *Aseg0, *Aseg1, *Bseg0, *Bseg1;
  size_t aStr0;          // r-tile byte stride of seg0 A
  int nchB0;             // per-c-tile chunk count of seg0 B
  int steps0, total;
  if (l == 0) {
    Aseg0 = (const char*)(Ep2 + (size_t)t * 32768); aStr0 = 8192;
    Bseg0 = (const char*)W0p; nchB0 = 8;
    Aseg1 = (const char*)hb(0, pr);
    Bseg1 = (const char*)U0p;
    steps0 = 1; total = 9;
  } else {
    Aseg0 = (const char*)hb(l - 1, pr); aStr0 = 65536;
    Bseg0 = (const char*)Wsp; nchB0 = 64;
    Aseg1 = (const char*)hb(l, pr);
    Bseg1 = (const char*)Usp;
    steps0 = 8; total = 16;
  }
  const int rloc0 = (rb & 1) * 4;    // layer-local r-tile base
  const int ct0   = cb * 4;          // global c-tile base
  const size_t lb16 = (size_t)lane * 16;

  // ---- per-wave base pointers (unit (x, kq=w) at x*stride + w KB) ----
  const char* a0B = Aseg0 + (size_t)rloc0 * aStr0 + (size_t)w * 1024 + lb16;
  const char* a1B = Aseg1 + (size_t)rloc0 * 65536 + (size_t)w * 1024 + lb16;
  const char* b0B[4];
  const char* b1B[4];
#pragma unroll
  for (int ct = 0; ct < 4; ++ct) {
    b0B[ct] = Bseg0 + ((size_t)(ct0 + ct) * nchB0 + w) * 1024 + lb16;
    b1B[ct] = Bseg1 + ((size_t)(ct0 + ct) * 64 + w) * 1024 + lb16;
  }

  // load one full step-set (4 A + 4 B units) into named set SN
#define LOADSET(SN, GS)                                                       \
  do {                                                                        \
    const int gs_ = (GS);                                                     \
    if (gs_ < steps0) {                                                       \
      size_t o_ = (size_t)gs_ * 8192;                                         \
      _Pragma("unroll")                                                       \
      for (int rt = 0; rt < 4; ++rt)                                          \
        asm volatile("global_load_dwordx4 %0, %1, off"                        \
                     : "=v"(SN.a[rt]) : "v"(a0B + (size_t)rt * aStr0 + o_));  \
      _Pragma("unroll")                                                       \
      for (int ct = 0; ct < 4; ++ct)                                          \
        asm volatile("global_load_dwordx4 %0, %1, off"                        \
                     : "=v"(SN.b[ct]) : "v"(b0B[ct] + o_));                   \
    } else {                                                                  \
      size_t o_ = (size_t)(gs_ - steps0) * 8192;                              \
      _Pragma("unroll")                                                       \
      for (int rt = 0; rt < 4; ++rt)                                          \
        asm volatile("global_load_dwordx4 %0, %1, off"                        \
                     : "=v"(SN.a[rt]) : "v"(a1B + (size_t)rt * 65536 + o_));  \
      _Pragma("unroll")                                                       \
      for (int ct = 0; ct < 4; ++ct)                                          \
        asm volatile("global_load_dwordx4 %0, %1, off"                        \
                     : "=v"(SN.b[ct]) : "v"(b1B[ct] + o_));                   \
    }                                                                         \
  } while (0)

  f32x4 acc[4][4];
#pragma unroll
  for (int r = 0; r < 4; ++r)
#pragma unroll
    for (int c = 0; c < 4; ++c) acc[r][c] = (f32x4){0.f, 0.f, 0.f, 0.f};

  // STEP(g): issue L(g+2) into NX2; per-wave counted wait for L(g); compute.
  // No barrier — waves are fully independent until the final reduction.
#define STEP(G, CUR, NX2)                                            \
  do {                                                               \
    const int g_ = (G);                                              \
    if (g_ + 2 < total) { LOADSET(NX2, g_ + 2); WAITV(16); }         \
    else if (g_ + 1 < total) { WAITV(8); }                           \
    else { WAITV(0); }                                               \
    __builtin_amdgcn_sched_barrier(0);                               \
    _Pragma("unroll")                                                \
    for (int rt = 0; rt < 4; ++rt)                                   \
      _Pragma("unroll")                                              \
      for (int ct = 0; ct < 4; ++ct)                                 \
        acc[rt][ct] = MFMA(CUR.a[rt], CUR.b[ct], acc[rt][ct]);       \
    __builtin_amdgcn_sched_barrier(0);                               \
  } while (0)

  FR S0, S1, S2;
  LOADSET(S0, 0);
  LOADSET(S1, 1);

  int g = 0;
  for (; g + 3 <= total; g += 3) {
    STEP(g,     S0, S2);
    STEP(g + 1, S1, S0);
    STEP(g + 2, S2, S1);
  }
  if (g < total) { STEP(g, S0, S2); ++g; }   // total=16 tail (step 15, set S0)
  if (g < total) { STEP(g, S1, S0); ++g; }
#undef STEP
#undef LOADSET

  // ---- K-split-8 reduction: partials -> LDS (8 x 16 KB), fixed order;
  //      wave w then owns cells {2w, 2w+1} of the 16 (rt,ct) cells. ----
  __syncthreads();
  {
    char* dst = &lds[0] + (size_t)w * 16384;
#pragma unroll
    for (int r = 0; r < 4; ++r)
#pragma unroll
      for (int c = 0; c < 4; ++c)
        *(f32x4*)(dst + (((size_t)(r * 4 + c) * 64 + lane) << 4)) = acc[r][c];
  }
  __syncthreads();

  const float* bias = (l == 0) ? b0 : b1;
  short* H = hb(l, pw);
  const int lo = lane & 15, hi = lane >> 4;
  const int mb = (rb & 1) * 64;
#pragma unroll
  for (int cc = 0; cc < 2; ++cc) {
    const int cell = w * 2 + cc;
    const int r = cell >> 2, c = cell & 3;
    const size_t coff = (((size_t)cell * 64 + lane) << 4);
    f32x4 sum = *(const f32x4*)(&lds[0] + coff);
#pragma unroll
    for (int p = 1; p < 8; ++p)
      sum += *(const f32x4*)(&lds[0] + (size_t)p * 16384 + coff);
    const int n = cb * 64 + c * 16 + lo;
    const float bv = bias[n];
    const int kk = n >> 5;
    const int lpn = ((n >> 3) & 3) << 4;
#pragma unroll
    for (int i = 0; i < 4; ++i) {
      int m = mb + r * 16 + hi * 4 + i;
      float z = sum[i] + bv;
      float e = __expf(2.f * z);
      float th = 1.f - 2.f / (e + 1.f);
      int rr = m >> 4;
      int lp = (m & 15) | lpn;
      H[(((size_t)rr * 64 + kk) * 64 + lp) * 8 + (n & 7)] = f2bf(th);
    }
  }
}

// ---------------------------------------------------------------------------
// Output head: out[b] = sigmoid(h3[b] . Wo + bo); h3 in A-pack layout.
// ---------------------------------------------------------------------------
__global__ __launch_bounds__(256) void head_kernel(
    const short* __restrict__ h3, const float* __restrict__ Wo,
    const float* __restrict__ bo, float* __restrict__ out) {
  __shared__ float sred[4];
  int b = blockIdx.x, tid = threadIdx.x;
  int kk = tid >> 2, hi = tid & 3;
  const bf16x8 v = *reinterpret_cast<const bf16x8*>(
      h3 + (((size_t)(b >> 4) * 64 + kk) * 64 + ((b & 15) | (hi << 4))) * 8);
  int k0 = kk * 32 + hi * 8;
  float acc = 0.f;
#pragma unroll
  for (int j = 0; j < 8; ++j) acc += bf2f(v[j]) * Wo[k0 + j];
  for (int off = 32; off > 0; off >>= 1) acc += __shfl_down(acc, off);
  if ((tid & 63) == 0) sred[tid >> 6] = acc;
  __syncthreads();
  if (tid == 0) {
    float z = sred[0] + sred[1] + sred[2] + sred[3] + bo[0];
    out[b] = 1.f / (1.f + expf(-z));
  }
}

extern "C" void kernel_launch(void* const* d_in, const int* in_sizes, int n_in,
                              void* d_out, int out_size, void* d_ws, size_t ws_size,
                              hipStream_t stream) {
  const int*   tokens = (const int*)d_in[0];
  const float* emb    = (const float*)d_in[1];
  const float* W0     = (const float*)d_in[2];
  const float* U0     = (const float*)d_in[3];
  const float* b0     = (const float*)d_in[4];
  const float* W1     = (const float*)d_in[5];
  const float* U1     = (const float*)d_in[6];
  const float* b1     = (const float*)d_in[7];
  const float* Wo     = (const float*)d_in[8];
  const float* bo     = (const float*)d_in[9];
  float* out = (float*)d_out;
  short* ws  = (short*)d_ws;

  const size_t W0P_SZ = (size_t)128 * 8 * 512;     // 524288  (padded to 8 kk)
  const size_t UP_SZ  = (size_t)128 * 64 * 512;    // 4194304
  const size_t EP_SZ  = (size_t)SEQ * 32768;       // 2621440 (padded to 8 kk)
  const size_t H_SZ   = (size_t)8 * 64 * 64 * 8;   // 262144 per buffer

  short* W0p = ws;
  short* U0p = W0p + W0P_SZ;
  short* W1p = U0p + UP_SZ;
  short* U1p = W1p + UP_SZ;
  short* Ep2 = U1p + UP_SZ;
  short* hbase = Ep2 + EP_SZ;

  {
    int unitsW0 = (UNITS / 16) * 8;             // 1024 (8 kk, zero-padded)
    pack_b_kernel<<<(unitsW0 + 3) / 4, 256, 0, stream>>>(W0, EMB, UNITS, 8, unitsW0, W0p);
    int unitsU = (UNITS / 16) * (UNITS / 32);   // 8192
    pack_b_kernel<<<(unitsU + 3) / 4, 256, 0, stream>>>(U0, UNITS, UNITS, UNITS / 32, unitsU, U0p);
    pack_b_kernel<<<(unitsU + 3) / 4, 256, 0, stream>>>(W1, UNITS, UNITS, UNITS / 32, unitsU, W1p);
    pack_b_kernel<<<(unitsU + 3) / 4, 256, 0, stream>>>(U1, UNITS, UNITS, UNITS / 32, unitsU, U1p);
    int ne = SEQ * 8 * 8 * 64;
    pack_e_kernel<<<(ne + 255) / 256, 256, 0, stream>>>(tokens, emb, Ep2);
  }

  // zero all 8 h double-buffers (provides h_l[-1] = 0)
  hipMemsetAsync(hbase, 0, 8u * H_SZ * 2u, stream);

  // ---- 83 diagonals: s = t + l ----
  for (int s = 0; s <= SEQ - 1 + 3; ++s) {
    diag_kernel<<<256, 512, 0, stream>>>(Ep2, W0p, U0p, W1p, U1p, b0, b1, hbase, s);
  }

  // final head: h3[SEQ-1] written at diagonal 82 (parity 0)
  head_kernel<<<BATCH, 256, 0, stream>>>(hbase + 6 * H_SZ, Wo, bo, out);
}